// Round 15
// baseline (248.061 us; speedup 1.0000x reference)
//
#include <hip/hip_runtime.h>
#include <hip/hip_bf16.h>
#include <stdint.h>

#define N_TOK   8192
#define DDIM    1024
#define HDIM    2048
#define NEXP    8
#define TOPK    2
#define NSLOTS  (N_TOK * TOPK)
#define RTSLOTS 20   // covers cnt up to 2560; counts ~2048, sigma~42 -> 12-sigma margin

typedef float f32x4 __attribute__((ext_vector_type(4)));
typedef __bf16 b16x8 __attribute__((ext_vector_type(8)));

__device__ __forceinline__ unsigned short f2bf(float f) {
  union { float f; uint32_t u; } x; x.f = f;
  uint32_t r = (x.u + 0x7FFFu + ((x.u >> 16) & 1u)) >> 16;
  return (unsigned short)r;
}
__device__ __forceinline__ float bf2f(unsigned short u) {
  union { uint32_t u; float f; } x; x.u = ((uint32_t)u) << 16; return x.f;
}

__device__ __forceinline__ void cvt8(const float* __restrict__ s,
                                     unsigned short* __restrict__ d, size_t i) {
  float4 a = ((const float4*)s)[2 * i];
  float4 b = ((const float4*)s)[2 * i + 1];
  union { unsigned short u[8]; uint4 v; } o;
  o.u[0] = f2bf(a.x); o.u[1] = f2bf(a.y); o.u[2] = f2bf(a.z); o.u[3] = f2bf(a.w);
  o.u[4] = f2bf(b.x); o.u[5] = f2bf(b.y); o.u[6] = f2bf(b.z); o.u[7] = f2bf(b.w);
  ((uint4*)d)[i] = o.v;
}

#define GLD16(gp, lp) __builtin_amdgcn_global_load_lds( \
    (const __attribute__((address_space(1))) void*)(gp), \
    (__attribute__((address_space(3))) void*)(lp), 16, 0, 0)

#define SCHED_FENCE() __builtin_amdgcn_sched_barrier(0)
#define RAW_BARRIER() { SCHED_FENCE(); __builtin_amdgcn_s_barrier(); SCHED_FENCE(); }

// ------- prep: UNPINNED cvt of x/w1/w2 (R12 partition) + routing as block 4096 -------
// R13 lesson: never XCD-pin streaming (per-XCD BW ~0.8 TB/s) -- round-robin blocks
// aggregate all 8 XCDs. R14 lesson: don't co-schedule streaming inside the GEMM grid
// either. The route (tiny, latency-bound) hides alongside the BW-bound cvt here.
__global__ void k_prep(const float* __restrict__ x, const float* __restrict__ w1,
                       const float* __restrict__ w2, unsigned short* __restrict__ xb,
                       unsigned short* __restrict__ w1b, unsigned short* __restrict__ w2b,
                       const int* __restrict__ idx, int* __restrict__ counts,
                       int* __restrict__ offsets,
                       int* __restrict__ slot_of_pos, int* __restrict__ pos_of_slot)
{
  const int bx = (int)blockIdx.x;
  const int t  = (int)threadIdx.x;

  if (bx == 4096) {
    __shared__ int sc[NEXP], so[NEXP], scur[NEXP];
    if (t < NEXP) sc[t] = 0;
    __syncthreads();
    for (int s = t; s < NSLOTS; s += 256) atomicAdd(&sc[idx[s]], 1);
    __syncthreads();
    if (t == 0) {
      int o = 0;
      for (int e = 0; e < NEXP; ++e) { so[e] = o; scur[e] = o; o += sc[e]; }
    }
    __syncthreads();
    for (int s = t; s < NSLOTS; s += 256) {
      int e = idx[s];
      int p = atomicAdd(&scur[e], 1);
      slot_of_pos[p] = s;
      pos_of_slot[s] = p;
    }
    if (t < NEXP) { counts[t] = sc[t]; offsets[t] = so[t]; }
    return;
  }

  const float* s; unsigned short* d; int n8, b0, nb;
  if (bx < 819)       { s = x;  d = xb;  n8 = 1048576; b0 = 0;    nb = 819;  }
  else if (bx < 2457) { s = w1; d = w1b; n8 = 2097152; b0 = 819;  nb = 1638; }
  else                { s = w2; d = w2b; n8 = 2097152; b0 = 2457; nb = 1639; }
  int stride = nb * 256;
  for (size_t i = (size_t)(bx - b0) * 256 + t; i < (size_t)n8; i += stride)
    cvt8(s, d, i);
}

// ---------------- grouped GEMM (NT): C[r,c] = A[r,:K] . B[c,:K] ----------------
// FROZEN R12 core (passed, 86.5us/GEMM, MfmaUtil 34.7%): 128x128 tile, BK=64,
// 4 waves, 2 independent blocks/CU, double-buffered LDS with counted vmcnt(8),
// register ping-pong at half-K-step granularity, XOR-swizzle byte^((row&7)<<4)
// with inverse pre-applied to the GLOBAL source, T5 setprio, XCD expert-pin
// decode (flat = bx + 8*(by + CT*bz); e = flat&7 -> XCD e runs only expert e,
// keeping its 4MiB weight slab L2-resident; ct=by fastest -> A-panel sharing).
template<int K, int NCOLS, int LOG2CT, bool GATHER, bool RELU2>
__global__ __launch_bounds__(256, 2)
void k_gemm(const unsigned short* __restrict__ A,
            const unsigned short* __restrict__ B,
            unsigned short* __restrict__ C,
            const int* __restrict__ counts,
            const int* __restrict__ offsets,
            const int* __restrict__ slot_of_pos)
{
  constexpr int CT = 1 << LOG2CT;
  const int flat = (int)(blockIdx.x + 8u * (blockIdx.y + gridDim.y * blockIdx.z));
  const int e    = flat & 7;
  const int rest = flat >> 3;
  const int ct   = rest & (CT - 1);
  const int rt   = rest >> LOG2CT;

  const int cnt = counts[e];
  if (rt * 128 >= cnt) return;
  const int off = offsets[e];

  __shared__ unsigned short lds[4 * 8192];   // 64 KiB: buf0 A@0 B@8192; buf1 A@16384 B@24576

  const int t    = threadIdx.x;
  const int lane = t & 63;
  const int wid  = t >> 6;

  const unsigned short* Bexp = B + (size_t)e * NCOLS * K;

  const unsigned short* aSrc[4];
  const unsigned short* bSrc[4];
  int dOffE[4];
#pragma unroll
  for (int j = 0; j < 4; ++j) {
    const int chunk = j * 4 + wid;               // 0..15 (wave-uniform)
    const int row   = chunk * 8 + (lane >> 3);   // LDS row 0..127
    const int qcol  = ((lane & 7) * 16) ^ ((row & 7) << 4);  // pre-swizzled byte in row
    int pr  = rt * 128 + row;
    int prc = pr < cnt ? pr : 0;
    if constexpr (GATHER) {
      int tok = slot_of_pos[off + prc] >> 1;     // slot -> token (K=2)
      aSrc[j] = A + (size_t)tok * K + (qcol >> 1);
    } else {
      aSrc[j] = A + (size_t)(off + prc) * K + (qcol >> 1);
    }
    bSrc[j] = Bexp + (size_t)(ct * 128 + row) * K + (qcol >> 1);
    dOffE[j] = chunk * 512;                      // 1024 B / 2
  }

  const int wr = wid >> 1, wc = wid & 1;
  const int kq = (lane >> 4) * 16;
  int aByte[4], bByte[4], aXor[4], bXor[4];
#pragma unroll
  for (int m = 0; m < 4; ++m) {
    int row = wr * 64 + m * 16 + (lane & 15);
    aByte[m] = row * 128; aXor[m] = (row & 7) << 4;
    int col = wc * 64 + m * 16 + (lane & 15);
    bByte[m] = col * 128; bXor[m] = (col & 7) << 4;
  }

  f32x4 acc[4][4];
#pragma unroll
  for (int m = 0; m < 4; ++m)
#pragma unroll
    for (int n = 0; n < 4; ++n) acc[m][n] = (f32x4){0.f, 0.f, 0.f, 0.f};

  auto STAGE = [&](int tt) {
    unsigned short* base = lds + ((tt & 1) << 14);
#pragma unroll
    for (int j = 0; j < 4; ++j) {
      GLD16(aSrc[j] + tt * 64, base + dOffE[j]);
      GLD16(bSrc[j] + tt * 64, base + 8192 + dOffE[j]);
    }
  };

  b16x8 a0[4], b0[4], a1[4], b1[4];

#define READ_KS0(CB) do { _Pragma("unroll") \
  for (int m_ = 0; m_ < 4; ++m_) { \
    a0[m_] = *(const b16x8*)((CB) + aByte[m_] + (kq ^ aXor[m_])); \
    b0[m_] = *(const b16x8*)((CB) + 16384 + bByte[m_] + (kq ^ bXor[m_])); \
  } } while (0)

#define READ_KS1(CB) do { _Pragma("unroll") \
  for (int m_ = 0; m_ < 4; ++m_) { \
    a1[m_] = *(const b16x8*)((CB) + aByte[m_] + ((64 + kq) ^ aXor[m_])); \
    b1[m_] = *(const b16x8*)((CB) + 16384 + bByte[m_] + ((64 + kq) ^ bXor[m_])); \
  } } while (0)

#define MFMA16(A_, B_) do { _Pragma("unroll") \
  for (int m_ = 0; m_ < 4; ++m_) _Pragma("unroll") \
    for (int n_ = 0; n_ < 4; ++n_) \
      acc[m_][n_] = __builtin_amdgcn_mfma_f32_16x16x32_bf16(A_[m_], B_[n_], acc[m_][n_], 0, 0, 0); \
  } while (0)

  constexpr int KT = K / 64;

  STAGE(0);
  STAGE(1);
  asm volatile("s_waitcnt vmcnt(8)" ::: "memory");
  RAW_BARRIER();
  READ_KS0(((const char*)lds));
  SCHED_FENCE();

  for (int kt = 0; kt < KT; ++kt) {
    const char* cb1 = (const char*)lds + (((kt + 1) & 1) << 15);

    READ_KS1(((const char*)lds + ((kt & 1) << 15)));   // +8 -> 16 lgkm in flight
    asm volatile("s_waitcnt lgkmcnt(8)" ::: "memory"); // ks0 frags ready
    SCHED_FENCE();
    __builtin_amdgcn_s_setprio(1);
    MFMA16(a0, b0);                                    // overlaps ks1-read latency
    __builtin_amdgcn_s_setprio(0);
    SCHED_FENCE();
    asm volatile("s_waitcnt lgkmcnt(0)" ::: "memory"); // ks1 ready; buf[kt] reads done
    SCHED_FENCE();
    RAW_BARRIER();                                     // all waves done with buf[kt]
    if (kt + 2 < KT) STAGE(kt + 2);                    // overwrite buf[kt]
    SCHED_FENCE();
    if (kt + 1 < KT) {
      if (kt + 2 < KT) {
        asm volatile("s_waitcnt vmcnt(8)" ::: "memory"); // tile kt+1 landed
      } else {
        asm volatile("s_waitcnt vmcnt(0)" ::: "memory"); // last staged tile
      }
      RAW_BARRIER();                                   // buf[kt+1] ready for all
      READ_KS0(cb1);                                   // next ks0, 8 reads in flight
      SCHED_FENCE();
    }
    __builtin_amdgcn_s_setprio(1);
    MFMA16(a1, b1);                                    // overlaps next ks0-read latency
    __builtin_amdgcn_s_setprio(0);
    SCHED_FENCE();
  }

#undef READ_KS0
#undef READ_KS1
#undef MFMA16

  // epilogue: C/D layout col = lane&15, row = (lane>>4)*4 + r  (m89-verified)
  const int rbase = rt * 128 + wr * 64 + (lane >> 4) * 4;
  const int cbase = ct * 128 + wc * 64 + (lane & 15);
#pragma unroll
  for (int m = 0; m < 4; ++m) {
#pragma unroll
    for (int r = 0; r < 4; ++r) {
      int pr = rbase + m * 16 + r;
      if (pr < cnt) {
        unsigned short* crow = C + (size_t)(off + pr) * NCOLS + cbase;
#pragma unroll
        for (int n = 0; n < 4; ++n) {
          float v = acc[m][n][r];
          if (RELU2) v = v > 0.f ? v * v : 0.f;
          crow[n * 16] = f2bf(v);
        }
      }
    }
  }
}

// ---------------- weighted combine of the two slots per token ----------------
__global__ void k_combine(const unsigned short* __restrict__ oslt,
                          const int* __restrict__ pos_of_slot,
                          const float* __restrict__ ew,
                          float* __restrict__ out)
{
  int n = blockIdx.x;
  int d = threadIdx.x * 4;
  int p0 = pos_of_slot[2 * n];
  int p1 = pos_of_slot[2 * n + 1];
  float w0 = ew[2 * n], w1 = ew[2 * n + 1];
  ushort4 a = *(const ushort4*)(oslt + (size_t)p0 * DDIM + d);
  ushort4 b = *(const ushort4*)(oslt + (size_t)p1 * DDIM + d);
  float4 o;
  o.x = w0 * bf2f(a.x) + w1 * bf2f(b.x);
  o.y = w0 * bf2f(a.y) + w1 * bf2f(b.y);
  o.z = w0 * bf2f(a.z) + w1 * bf2f(b.z);
  o.w = w0 * bf2f(a.w) + w1 * bf2f(b.w);
  *(float4*)(out + (size_t)n * DDIM + d) = o;
}

extern "C" void kernel_launch(void* const* d_in, const int* in_sizes, int n_in,
                              void* d_out, int out_size, void* d_ws, size_t ws_size,
                              hipStream_t stream)
{
  const float* x  = (const float*)d_in[0];
  const int* eidx = (const int*)d_in[1];
  const float* ew = (const float*)d_in[2];
  const float* w1 = (const float*)d_in[3];
  const float* w2 = (const float*)d_in[4];
  float* out = (float*)d_out;

  char* ws = (char*)d_ws;
  // layout (bytes):
  //   [0,            16777216)  xb   (8192x1024 bf16)          } dead after up-GEMM
  //   [16777216,     50331648)  w1b  (8x2048x1024 bf16)        }
  //   [0,            33554432)  oslt (16384x1024 bf16)  -- aliases xb+w1b, live after up-GEMM
  //   [50331648,     83886080)  w2b  (8x1024x2048 bf16)
  //   [83886080,    150994944)  hid  (16384x2048 bf16)
  //   [150994944,  ...       )  routing ints
  unsigned short* xb   = (unsigned short*)ws;
  unsigned short* w1b  = (unsigned short*)(ws + (size_t)16777216);
  unsigned short* oslt = (unsigned short*)ws;
  unsigned short* w2b  = (unsigned short*)(ws + (size_t)50331648);
  unsigned short* hid  = (unsigned short*)(ws + (size_t)83886080);
  int* counts      = (int*)(ws + (size_t)150994944);
  int* offsets     = counts + NEXP;
  int* slot_of_pos = offsets + NEXP;
  int* pos_of_slot = slot_of_pos + NSLOTS;

  // unpinned cvt of x,w1,w2 + route (block 4096, concurrent with the BW-bound cvt)
  k_prep<<<4097, 256, 0, stream>>>(x, w1, w2, xb, w1b, w2b,
                                   eidx, counts, offsets, slot_of_pos, pos_of_slot);

  // grid: (bx=8 experts, by=CT col tiles, bz=RTSLOTS row tiles);
  // flat = bx + 8*(by + CT*bz) -> XCD = flat%8 = expert (round-robin placement)
  dim3 gup(8, HDIM / 128, RTSLOTS);
  k_gemm<DDIM, HDIM, 4, true,  true ><<<gup, 256, 0, stream>>>(xb,  w1b, hid,  counts, offsets, slot_of_pos);
  dim3 gdn(8, DDIM / 128, RTSLOTS);
  k_gemm<HDIM, DDIM, 3, false, false><<<gdn, 256, 0, stream>>>(hid, w2b, oslt, counts, offsets, slot_of_pos);

  k_combine<<<N_TOK, 256, 0, stream>>>(oslt, pos_of_slot, ew, out);
}

// Round 16
// 229.311 us; speedup vs baseline: 1.0818x; 1.0818x over previous
//
#include <hip/hip_runtime.h>
#include <hip/hip_bf16.h>
#include <stdint.h>

#define N_TOK   8192
#define DDIM    1024
#define HDIM    2048
#define NEXP    8
#define TOPK    2
#define NSLOTS  (N_TOK * TOPK)
#define RTSLOTS 20   // covers cnt up to 2560; counts ~2048, sigma~42 -> 12-sigma margin

typedef float f32x4 __attribute__((ext_vector_type(4)));
typedef __bf16 b16x8 __attribute__((ext_vector_type(8)));

__device__ __forceinline__ unsigned short f2bf(float f) {
  union { float f; uint32_t u; } x; x.f = f;
  uint32_t r = (x.u + 0x7FFFu + ((x.u >> 16) & 1u)) >> 16;
  return (unsigned short)r;
}
__device__ __forceinline__ float bf2f(unsigned short u) {
  union { uint32_t u; float f; } x; x.u = ((uint32_t)u) << 16; return x.f;
}

__device__ __forceinline__ void cvt8(const float* __restrict__ s,
                                     unsigned short* __restrict__ d, size_t i) {
  float4 a = ((const float4*)s)[2 * i];
  float4 b = ((const float4*)s)[2 * i + 1];
  union { unsigned short u[8]; uint4 v; } o;
  o.u[0] = f2bf(a.x); o.u[1] = f2bf(a.y); o.u[2] = f2bf(a.z); o.u[3] = f2bf(a.w);
  o.u[4] = f2bf(b.x); o.u[5] = f2bf(b.y); o.u[6] = f2bf(b.z); o.u[7] = f2bf(b.w);
  ((uint4*)d)[i] = o.v;
}

#define GLD16(gp, lp) __builtin_amdgcn_global_load_lds( \
    (const __attribute__((address_space(1))) void*)(gp), \
    (__attribute__((address_space(3))) void*)(lp), 16, 0, 0)

#define SCHED_FENCE() __builtin_amdgcn_sched_barrier(0)
#define RAW_BARRIER() { SCHED_FENCE(); __builtin_amdgcn_s_barrier(); SCHED_FENCE(); }

// ---------------- routing: one 1024-thread block, int4-vectorized ----------------
// R15 lesson: the route inside the cvt dispatch (256 thr, scalar loads) added ~50us
// of tail. Separate kernel, 1024 threads, int4 loads: 4 passes -> ~5us.
__global__ void k_route(const int* __restrict__ idx, int* __restrict__ counts,
                        int* __restrict__ offsets,
                        int* __restrict__ slot_of_pos, int* __restrict__ pos_of_slot) {
  __shared__ int sc[NEXP], so[NEXP], scur[NEXP];
  int t = threadIdx.x;
  if (t < NEXP) sc[t] = 0;
  __syncthreads();
  for (int q = t; q < NSLOTS / 4; q += 1024) {
    int4 v = ((const int4*)idx)[q];
    atomicAdd(&sc[v.x], 1); atomicAdd(&sc[v.y], 1);
    atomicAdd(&sc[v.z], 1); atomicAdd(&sc[v.w], 1);
  }
  __syncthreads();
  if (t == 0) {
    int o = 0;
    for (int e = 0; e < NEXP; ++e) { so[e] = o; scur[e] = o; o += sc[e]; }
  }
  __syncthreads();
  for (int q = t; q < NSLOTS / 4; q += 1024) {
    int4 v = ((const int4*)idx)[q];
    int s = q * 4;
    int p;
    p = atomicAdd(&scur[v.x], 1); slot_of_pos[p] = s;     pos_of_slot[s]     = p;
    p = atomicAdd(&scur[v.y], 1); slot_of_pos[p] = s + 1; pos_of_slot[s + 1] = p;
    p = atomicAdd(&scur[v.z], 1); slot_of_pos[p] = s + 2; pos_of_slot[s + 2] = p;
    p = atomicAdd(&scur[v.w], 1); slot_of_pos[p] = s + 3; pos_of_slot[s + 3] = p;
  }
  if (t < NEXP) { counts[t] = sc[t]; offsets[t] = so[t]; }
}

// ---------------- fp32 -> bf16 conversion: UNPINNED block-range partition ----------------
// R13 lesson: never XCD-pin streaming (per-XCD BW ~0.8 TB/s); round-robin blocks
// aggregate all 8 XCDs. R14 lesson: don't co-schedule streaming inside the GEMM grid.
__global__ void k_cvt3(const float* __restrict__ s0, const float* __restrict__ s1,
                       const float* __restrict__ s2, unsigned short* __restrict__ d0,
                       unsigned short* __restrict__ d1, unsigned short* __restrict__ d2) {
  const float* s; unsigned short* d; int n8, b0, nb;
  if (blockIdx.x < 819)       { s = s0; d = d0; n8 = 1048576; b0 = 0;    nb = 819;  }
  else if (blockIdx.x < 2457) { s = s1; d = d1; n8 = 2097152; b0 = 819;  nb = 1638; }
  else                        { s = s2; d = d2; n8 = 2097152; b0 = 2457; nb = 1639; }
  int stride = nb * 256;
  for (size_t i = (size_t)((int)blockIdx.x - b0) * 256 + threadIdx.x; i < (size_t)n8; i += stride)
    cvt8(s, d, i);
}

// ---------------- grouped GEMM (NT): C[r,c] = A[r,:K] . B[c,:K] ----------------
// FROZEN R12 core (passed, 86.5us/GEMM, MfmaUtil 34.7%): 128x128 tile, BK=64,
// 4 waves, 2 independent blocks/CU, double-buffered LDS with counted vmcnt(8),
// register ping-pong at half-K-step granularity, XOR-swizzle byte^((row&7)<<4)
// with inverse pre-applied to the GLOBAL source, T5 setprio, XCD expert-pin
// decode (flat = bx + 8*(by + CT*bz); e = flat&7 -> XCD e runs only expert e,
// keeping its 4MiB weight slab L2-resident; ct=by fastest -> A-panel sharing).
template<int K, int NCOLS, int LOG2CT, bool GATHER, bool RELU2>
__global__ __launch_bounds__(256, 2)
void k_gemm(const unsigned short* __restrict__ A,
            const unsigned short* __restrict__ B,
            unsigned short* __restrict__ C,
            const int* __restrict__ counts,
            const int* __restrict__ offsets,
            const int* __restrict__ slot_of_pos)
{
  constexpr int CT = 1 << LOG2CT;
  const int flat = (int)(blockIdx.x + 8u * (blockIdx.y + gridDim.y * blockIdx.z));
  const int e    = flat & 7;
  const int rest = flat >> 3;
  const int ct   = rest & (CT - 1);
  const int rt   = rest >> LOG2CT;

  const int cnt = counts[e];
  if (rt * 128 >= cnt) return;
  const int off = offsets[e];

  __shared__ unsigned short lds[4 * 8192];   // 64 KiB: buf0 A@0 B@8192; buf1 A@16384 B@24576

  const int t    = threadIdx.x;
  const int lane = t & 63;
  const int wid  = t >> 6;

  const unsigned short* Bexp = B + (size_t)e * NCOLS * K;

  const unsigned short* aSrc[4];
  const unsigned short* bSrc[4];
  int dOffE[4];
#pragma unroll
  for (int j = 0; j < 4; ++j) {
    const int chunk = j * 4 + wid;               // 0..15 (wave-uniform)
    const int row   = chunk * 8 + (lane >> 3);   // LDS row 0..127
    const int qcol  = ((lane & 7) * 16) ^ ((row & 7) << 4);  // pre-swizzled byte in row
    int pr  = rt * 128 + row;
    int prc = pr < cnt ? pr : 0;
    if constexpr (GATHER) {
      int tok = slot_of_pos[off + prc] >> 1;     // slot -> token (K=2)
      aSrc[j] = A + (size_t)tok * K + (qcol >> 1);
    } else {
      aSrc[j] = A + (size_t)(off + prc) * K + (qcol >> 1);
    }
    bSrc[j] = Bexp + (size_t)(ct * 128 + row) * K + (qcol >> 1);
    dOffE[j] = chunk * 512;                      // 1024 B / 2
  }

  const int wr = wid >> 1, wc = wid & 1;
  const int kq = (lane >> 4) * 16;
  int aByte[4], bByte[4], aXor[4], bXor[4];
#pragma unroll
  for (int m = 0; m < 4; ++m) {
    int row = wr * 64 + m * 16 + (lane & 15);
    aByte[m] = row * 128; aXor[m] = (row & 7) << 4;
    int col = wc * 64 + m * 16 + (lane & 15);
    bByte[m] = col * 128; bXor[m] = (col & 7) << 4;
  }

  f32x4 acc[4][4];
#pragma unroll
  for (int m = 0; m < 4; ++m)
#pragma unroll
    for (int n = 0; n < 4; ++n) acc[m][n] = (f32x4){0.f, 0.f, 0.f, 0.f};

  auto STAGE = [&](int tt) {
    unsigned short* base = lds + ((tt & 1) << 14);
#pragma unroll
    for (int j = 0; j < 4; ++j) {
      GLD16(aSrc[j] + tt * 64, base + dOffE[j]);
      GLD16(bSrc[j] + tt * 64, base + 8192 + dOffE[j]);
    }
  };

  b16x8 a0[4], b0[4], a1[4], b1[4];

#define READ_KS0(CB) do { _Pragma("unroll") \
  for (int m_ = 0; m_ < 4; ++m_) { \
    a0[m_] = *(const b16x8*)((CB) + aByte[m_] + (kq ^ aXor[m_])); \
    b0[m_] = *(const b16x8*)((CB) + 16384 + bByte[m_] + (kq ^ bXor[m_])); \
  } } while (0)

#define READ_KS1(CB) do { _Pragma("unroll") \
  for (int m_ = 0; m_ < 4; ++m_) { \
    a1[m_] = *(const b16x8*)((CB) + aByte[m_] + ((64 + kq) ^ aXor[m_])); \
    b1[m_] = *(const b16x8*)((CB) + 16384 + bByte[m_] + ((64 + kq) ^ bXor[m_])); \
  } } while (0)

#define MFMA16(A_, B_) do { _Pragma("unroll") \
  for (int m_ = 0; m_ < 4; ++m_) _Pragma("unroll") \
    for (int n_ = 0; n_ < 4; ++n_) \
      acc[m_][n_] = __builtin_amdgcn_mfma_f32_16x16x32_bf16(A_[m_], B_[n_], acc[m_][n_], 0, 0, 0); \
  } while (0)

  constexpr int KT = K / 64;

  STAGE(0);
  STAGE(1);
  asm volatile("s_waitcnt vmcnt(8)" ::: "memory");
  RAW_BARRIER();
  READ_KS0(((const char*)lds));
  SCHED_FENCE();

  for (int kt = 0; kt < KT; ++kt) {
    const char* cb1 = (const char*)lds + (((kt + 1) & 1) << 15);

    READ_KS1(((const char*)lds + ((kt & 1) << 15)));   // +8 -> 16 lgkm in flight
    asm volatile("s_waitcnt lgkmcnt(8)" ::: "memory"); // ks0 frags ready
    SCHED_FENCE();
    __builtin_amdgcn_s_setprio(1);
    MFMA16(a0, b0);                                    // overlaps ks1-read latency
    __builtin_amdgcn_s_setprio(0);
    SCHED_FENCE();
    asm volatile("s_waitcnt lgkmcnt(0)" ::: "memory"); // ks1 ready; buf[kt] reads done
    SCHED_FENCE();
    RAW_BARRIER();                                     // all waves done with buf[kt]
    if (kt + 2 < KT) STAGE(kt + 2);                    // overwrite buf[kt]
    SCHED_FENCE();
    if (kt + 1 < KT) {
      if (kt + 2 < KT) {
        asm volatile("s_waitcnt vmcnt(8)" ::: "memory"); // tile kt+1 landed
      } else {
        asm volatile("s_waitcnt vmcnt(0)" ::: "memory"); // last staged tile
      }
      RAW_BARRIER();                                   // buf[kt+1] ready for all
      READ_KS0(cb1);                                   // next ks0, 8 reads in flight
      SCHED_FENCE();
    }
    __builtin_amdgcn_s_setprio(1);
    MFMA16(a1, b1);                                    // overlaps next ks0-read latency
    __builtin_amdgcn_s_setprio(0);
    SCHED_FENCE();
  }

#undef READ_KS0
#undef READ_KS1
#undef MFMA16

  // epilogue: C/D layout col = lane&15, row = (lane>>4)*4 + r  (m89-verified)
  const int rbase = rt * 128 + wr * 64 + (lane >> 4) * 4;
  const int cbase = ct * 128 + wc * 64 + (lane & 15);
#pragma unroll
  for (int m = 0; m < 4; ++m) {
#pragma unroll
    for (int r = 0; r < 4; ++r) {
      int pr = rbase + m * 16 + r;
      if (pr < cnt) {
        unsigned short* crow = C + (size_t)(off + pr) * NCOLS + cbase;
#pragma unroll
        for (int n = 0; n < 4; ++n) {
          float v = acc[m][n][r];
          if (RELU2) v = v > 0.f ? v * v : 0.f;
          crow[n * 16] = f2bf(v);
        }
      }
    }
  }
}

// ---------------- weighted combine of the two slots per token ----------------
__global__ void k_combine(const unsigned short* __restrict__ oslt,
                          const int* __restrict__ pos_of_slot,
                          const float* __restrict__ ew,
                          float* __restrict__ out)
{
  int n = blockIdx.x;
  int d = threadIdx.x * 4;
  int p0 = pos_of_slot[2 * n];
  int p1 = pos_of_slot[2 * n + 1];
  float w0 = ew[2 * n], w1 = ew[2 * n + 1];
  ushort4 a = *(const ushort4*)(oslt + (size_t)p0 * DDIM + d);
  ushort4 b = *(const ushort4*)(oslt + (size_t)p1 * DDIM + d);
  float4 o;
  o.x = w0 * bf2f(a.x) + w1 * bf2f(b.x);
  o.y = w0 * bf2f(a.y) + w1 * bf2f(b.y);
  o.z = w0 * bf2f(a.z) + w1 * bf2f(b.z);
  o.w = w0 * bf2f(a.w) + w1 * bf2f(b.w);
  *(float4*)(out + (size_t)n * DDIM + d) = o;
}

extern "C" void kernel_launch(void* const* d_in, const int* in_sizes, int n_in,
                              void* d_out, int out_size, void* d_ws, size_t ws_size,
                              hipStream_t stream)
{
  const float* x  = (const float*)d_in[0];
  const int* eidx = (const int*)d_in[1];
  const float* ew = (const float*)d_in[2];
  const float* w1 = (const float*)d_in[3];
  const float* w2 = (const float*)d_in[4];
  float* out = (float*)d_out;

  char* ws = (char*)d_ws;
  // layout (bytes):
  //   [0,            16777216)  xb   (8192x1024 bf16)          } dead after up-GEMM
  //   [16777216,     50331648)  w1b  (8x2048x1024 bf16)        }
  //   [0,            33554432)  oslt (16384x1024 bf16)  -- aliases xb+w1b, live after up-GEMM
  //   [50331648,     83886080)  w2b  (8x1024x2048 bf16)
  //   [83886080,    150994944)  hid  (16384x2048 bf16)
  //   [150994944,  ...       )  routing ints
  unsigned short* xb   = (unsigned short*)ws;
  unsigned short* w1b  = (unsigned short*)(ws + (size_t)16777216);
  unsigned short* oslt = (unsigned short*)ws;
  unsigned short* w2b  = (unsigned short*)(ws + (size_t)50331648);
  unsigned short* hid  = (unsigned short*)(ws + (size_t)83886080);
  int* counts      = (int*)(ws + (size_t)150994944);
  int* offsets     = counts + NEXP;
  int* slot_of_pos = offsets + NEXP;
  int* pos_of_slot = slot_of_pos + NSLOTS;

  k_route<<<1, 1024, 0, stream>>>(eidx, counts, offsets, slot_of_pos, pos_of_slot);

  k_cvt3<<<4096, 256, 0, stream>>>(x, w1, w2, xb, w1b, w2b);

  // grid: (bx=8 experts, by=CT col tiles, bz=RTSLOTS row tiles);
  // flat = bx + 8*(by + CT*bz) -> XCD = flat%8 = expert (round-robin placement)
  dim3 gup(8, HDIM / 128, RTSLOTS);
  k_gemm<DDIM, HDIM, 4, true,  true ><<<gup, 256, 0, stream>>>(xb,  w1b, hid,  counts, offsets, slot_of_pos);
  dim3 gdn(8, DDIM / 128, RTSLOTS);
  k_gemm<HDIM, DDIM, 3, false, false><<<gdn, 256, 0, stream>>>(hid, w2b, oslt, counts, offsets, slot_of_pos);

  k_combine<<<N_TOK, 256, 0, stream>>>(oslt, pos_of_slot, ew, out);
}